// Round 2
// baseline (200.385 us; speedup 1.0000x reference)
//
#include <hip/hip_runtime.h>

// Problem constants (B=64, T=512, F=256, MASKING_RATE=0.4 -> n_mask=205)
#define T_DIM   512
#define F_DIM   256
#define N_MASK  205
#define N_PER   8388608   // 64*512*256 elements per tensor
#define V_PER   2097152   // N_PER / 4 (float4 elements per tensor)
#define F4_ROW  64        // F_DIM / 4 float4 per (b,t) row

// Kernel 1: compute stable-argsort-rank mask for 512 elements.
// mask[t] = 1.0 iff rank(r[t]) < 205 (rank = count of j with r[j]<r[t],
// ties broken by index j<t -- matches jnp.argsort stability).
__global__ void mask_kernel(const float* __restrict__ rt,
                            float* __restrict__ mask_out) {
    __shared__ float r[T_DIM];
    const int t = threadIdx.x;
    r[t] = rt[t];
    __syncthreads();
    const float rv = r[t];
    int count = 0;
#pragma unroll 8
    for (int j = 0; j < T_DIM; ++j) {
        const float rj = r[j];
        count += (rj < rv) || (rj == rv && j < t);
    }
    mask_out[t] = (count < N_MASK) ? 1.0f : 0.0f;
}

// Kernel 2: elementwise where(mask, 0, x) for 3 tensors, float4-vectorized.
// A wave of 64 consecutive threads spans exactly one (b,t) row (64 float4),
// so the mask branch is wave-uniform: masked rows write zeros with NO read.
__global__ __launch_bounds__(256) void apply_kernel(
        const float4* __restrict__ a, const float4* __restrict__ b,
        const float4* __restrict__ c,
        float4* __restrict__ oa, float4* __restrict__ ob,
        float4* __restrict__ oc,
        const float* __restrict__ mask) {
    const int stride = gridDim.x * blockDim.x;
    const float4 z = make_float4(0.f, 0.f, 0.f, 0.f);
    for (int i = blockIdx.x * blockDim.x + threadIdx.x; i < V_PER; i += stride) {
        const int t = (i >> 6) & (T_DIM - 1);   // (i / F4_ROW) % T_DIM
        if (mask[t] != 0.0f) {
            oa[i] = z; ob[i] = z; oc[i] = z;    // no read needed
        } else {
            oa[i] = a[i]; ob[i] = b[i]; oc[i] = c[i];
        }
    }
}

extern "C" void kernel_launch(void* const* d_in, const int* in_sizes, int n_in,
                              void* d_out, int out_size, void* d_ws, size_t ws_size,
                              hipStream_t stream) {
    const float4* x_tre = (const float4*)d_in[0];
    const float4* x_sea = (const float4*)d_in[1];
    const float4* x_res = (const float4*)d_in[2];
    const float*  rt    = (const float*)d_in[3];

    float* out = (float*)d_out;
    float4* z_tre = (float4*)(out);
    float4* z_sea = (float4*)(out + (size_t)N_PER);
    float4* z_res = (float4*)(out + (size_t)2 * N_PER);
    float*  msk   = out + (size_t)3 * N_PER;   // 512 floats (bool as 0/1)

    // 1) mask (one block, LDS-resident rank count)
    mask_kernel<<<1, T_DIM, 0, stream>>>(rt, msk);

    // 2) apply (grid-stride, 2048 blocks x 256 threads, 4 iters/thread)
    apply_kernel<<<2048, 256, 0, stream>>>(x_tre, x_sea, x_res,
                                           z_tre, z_sea, z_res, msk);
}

// Round 5
// 198.166 us; speedup vs baseline: 1.0112x; 1.0112x over previous
//
#include <hip/hip_runtime.h>

// Problem constants (B=64, T=512, F=256, MASKING_RATE=0.4 -> n_mask=205)
#define T_DIM   512
#define F_DIM   256
#define N_MASK  205
#define N_PER   8388608   // 64*512*256 elements per tensor
#define V_PER   2097152   // N_PER / 4 (float4 elements per tensor)

// Native clang vector type: __builtin_nontemporal_store requires it
// (HIP's float4 is a struct and is rejected).
typedef float f32x4 __attribute__((ext_vector_type(4)));

// Kernel 1: stable-argsort-rank mask for 512 elements.
// mask[t] = 1.0 iff rank(r[t]) < 205 (rank = #{j : r[j]<r[t] or (r[j]==r[t] and j<t)},
// matching jnp.argsort stability).
__global__ void mask_kernel(const float* __restrict__ rt,
                            float* __restrict__ mask_out) {
    __shared__ float r[T_DIM];
    const int t = threadIdx.x;
    r[t] = rt[t];
    __syncthreads();
    const float rv = r[t];
    int count = 0;
#pragma unroll 8
    for (int j = 0; j < T_DIM; ++j) {
        const float rj = r[j];
        count += (rj < rv) || (rj == rv && j < t);
    }
    mask_out[t] = (count < N_MASK) ? 1.0f : 0.0f;
}

// Kernel 2: where(mask, 0, x) for 3 tensors, float4-vectorized.
// A wave of 64 consecutive lanes spans exactly one (b,t) row (64 float4), so
// the mask branch is wave-uniform: masked rows write zeros with NO read.
// Stores are non-temporal (streaming, no write-allocate) -- output is never
// re-read, and skipping L2/L3 allocation keeps the (L3-resident) inputs hot.
__global__ __launch_bounds__(256) void apply_kernel(
        const f32x4* __restrict__ a, const f32x4* __restrict__ b,
        const f32x4* __restrict__ c,
        f32x4* __restrict__ oa, f32x4* __restrict__ ob,
        f32x4* __restrict__ oc,
        const float* __restrict__ mask) {
    const int stride = gridDim.x * blockDim.x;
    const f32x4 z = (f32x4)(0.f);
    for (int i = blockIdx.x * blockDim.x + threadIdx.x; i < V_PER; i += stride) {
        const int t = (i >> 6) & (T_DIM - 1);   // (i / 64) % T_DIM, wave-uniform
        if (mask[t] != 0.0f) {
            __builtin_nontemporal_store(z, &oa[i]);
            __builtin_nontemporal_store(z, &ob[i]);
            __builtin_nontemporal_store(z, &oc[i]);
        } else {
            __builtin_nontemporal_store(a[i], &oa[i]);
            __builtin_nontemporal_store(b[i], &ob[i]);
            __builtin_nontemporal_store(c[i], &oc[i]);
        }
    }
}

extern "C" void kernel_launch(void* const* d_in, const int* in_sizes, int n_in,
                              void* d_out, int out_size, void* d_ws, size_t ws_size,
                              hipStream_t stream) {
    const f32x4* x_tre = (const f32x4*)d_in[0];
    const f32x4* x_sea = (const f32x4*)d_in[1];
    const f32x4* x_res = (const f32x4*)d_in[2];
    const float* rt    = (const float*)d_in[3];

    float* out = (float*)d_out;
    f32x4* z_tre = (f32x4*)(out);
    f32x4* z_sea = (f32x4*)(out + (size_t)N_PER);
    f32x4* z_res = (f32x4*)(out + (size_t)2 * N_PER);
    float* msk   = out + (size_t)3 * N_PER;   // 512 floats (bool as 0/1)

    // 1) mask (one block, LDS-resident rank count)
    mask_kernel<<<1, T_DIM, 0, stream>>>(rt, msk);

    // 2) apply (grid-stride, 2048 blocks x 256 threads = 8192 waves, 4 iters/thread)
    apply_kernel<<<2048, 256, 0, stream>>>(x_tre, x_sea, x_res,
                                           z_tre, z_sea, z_res, msk);
}